// Round 10
// baseline (93.943 us; speedup 1.0000x reference)
//
#include <hip/hip_runtime.h>

// ScaledDotProductAttention B=8, L=2048, D=64, fp32 in/out.
//
// Two-launch scheme (ws >= 8 MB):
//  1) prepass: K -> fp16 copy (K16), V -> fp16 transposed (VT16) in d_ws.
//  2) attn_w8: grid 256 (8 batch x 32 qblocks of 64 queries), but now
//     512 threads = 8 waves/block -> 2 waves/SIMD (R9 had 1: every L2/VALU
//     latency fully exposed). Wave w owns keys [w*256, +256) = 8 tiles of 32.
//     Hot loop: ZERO LDS, ZERO cross-lane; K *and* V fragments prefetched
//     one tile ahead in registers.
//       - S^T = K*Q^T via mfma_f32_16x16x32_f16; C-layout: lane holds
//         S^T[key=quad*4+r][q=qs*16+l15].
//       - p = exp2(s) (0.125*log2e folded into Q); packed half4 IS the
//         B-frag of mfma_f32_16x16x16f16 -> PV straight from registers.
//       - PV: O^T += VT16 half4 A-frags x P^T.
//     Epilogue: 4 passes over a 36 KB LDS buffer; 8-wave (O,l) combine,
//     normalize, float4 store.
// Fallback: proven R3 kernel if ws too small.

#define B_ 8
#define L_ 2048
#define D_ 64
#define NT 256
#define TK 32              // keys per tile

typedef _Float16 half8_t __attribute__((ext_vector_type(8)));
typedef _Float16 half4_t __attribute__((ext_vector_type(4)));
typedef float f32x4 __attribute__((ext_vector_type(4)));

#define SCALE_LOG2E 0.1803368801111244f   // 0.125 * log2(e)

// ---------------------------------------------------------------- prepass --
// blocks 0..511: K cast; 512..767: V transpose.
__global__ __launch_bounds__(NT) void prepass(
    const float* __restrict__ K, const float* __restrict__ V,
    _Float16* __restrict__ K16, _Float16* __restrict__ VT16)
{
    const int blk = blockIdx.x;
    const int t = threadIdx.x;
    if (blk < 512) {
        const int i = blk * NT + t;                  // half8 index, 131072 total
        const float4* s4 = (const float4*)K;
        const float4 a = s4[2 * i], b = s4[2 * i + 1];
        half8_t w;
        w[0] = (_Float16)a.x; w[1] = (_Float16)a.y;
        w[2] = (_Float16)a.z; w[3] = (_Float16)a.w;
        w[4] = (_Float16)b.x; w[5] = (_Float16)b.y;
        w[6] = (_Float16)b.z; w[7] = (_Float16)b.w;
        ((half8_t*)K16)[i] = w;
    } else {
        __shared__ __align__(16) _Float16 Lt[64 * 72];   // [dim][key] tile
        const int vblk = blk - 512;
        const int bb = vblk >> 5;            // batch
        const int kt = vblk & 31;            // 64-key tile
        const int r  = t >> 2;               // key row 0..63
        const int ch = t & 3;                // 16-dim chunk
        const float* vrow = V + ((size_t)bb * L_ + kt * 64 + r) * D_ + ch * 16;
        #pragma unroll
        for (int i = 0; i < 4; ++i) {
            const float4 f = ((const float4*)vrow)[i];
            const int d0 = ch * 16 + i * 4;
            Lt[(d0 + 0) * 72 + r] = (_Float16)f.x;
            Lt[(d0 + 1) * 72 + r] = (_Float16)f.y;
            Lt[(d0 + 2) * 72 + r] = (_Float16)f.z;
            Lt[(d0 + 3) * 72 + r] = (_Float16)f.w;
        }
        __syncthreads();
        const int d  = t >> 2;               // dim row 0..63
        const int c2 = t & 3;                // 16-key chunk
        const half8_t w0 = *(const half8_t*)&Lt[d * 72 + c2 * 16];
        const half8_t w1 = *(const half8_t*)&Lt[d * 72 + c2 * 16 + 8];
        _Float16* orow = VT16 + ((size_t)bb * D_ + d) * L_ + kt * 64 + c2 * 16;
        *(half8_t*)orow = w0;
        *(half8_t*)(orow + 8) = w1;
    }
}

// -------------------------------------------------------------- main body --

// Load K B-row fragments for the 32-key tile at KB.
#define LOADK(KB, BK)                                                           \
    {                                                                           \
        _Pragma("unroll") for (int s = 0; s < 2; ++s)                           \
        _Pragma("unroll") for (int c = 0; c < 2; ++c)                           \
            BK[s][c] = *(const half8_t*)&Kb[(size_t)((KB) + s * 16 + l15) * D_ + c * 32 + quad * 8]; \
    }

// Load V A-row fragments (K=16 MFMA) for the 32-key tile at KB.
#define LOADV(KB, AV)                                                           \
    {                                                                           \
        _Pragma("unroll") for (int d = 0; d < 4; ++d)                           \
        _Pragma("unroll") for (int ks = 0; ks < 2; ++ks)                        \
            AV[d][ks] = *(const half4_t*)&Vb[(size_t)(d * 16 + l15) * L_ + (KB) + ks * 16 + quad * 4]; \
    }

// Process one 32-key tile using pre-loaded K frags BK and V frags AV.
#define PROC(BK, AV)                                                            \
    {                                                                           \
        f32x4 sc[2][4];                                                         \
        _Pragma("unroll") for (int ks = 0; ks < 2; ++ks)                        \
        _Pragma("unroll") for (int qs = 0; qs < 4; ++qs) {                      \
            f32x4 acc = (f32x4){0.f, 0.f, 0.f, 0.f};                            \
            acc = __builtin_amdgcn_mfma_f32_16x16x32_f16(BK[ks][0], bq[qs][0], acc, 0, 0, 0); \
            acc = __builtin_amdgcn_mfma_f32_16x16x32_f16(BK[ks][1], bq[qs][1], acc, 0, 0, 0); \
            sc[ks][qs] = acc;                                                   \
        }                                                                       \
        half4_t pb[2][4];                                                       \
        _Pragma("unroll") for (int ks = 0; ks < 2; ++ks)                        \
        _Pragma("unroll") for (int qs = 0; qs < 4; ++qs) {                      \
            const float p0 = __builtin_exp2f(sc[ks][qs][0]);                    \
            const float p1 = __builtin_exp2f(sc[ks][qs][1]);                    \
            const float p2 = __builtin_exp2f(sc[ks][qs][2]);                    \
            const float p3 = __builtin_exp2f(sc[ks][qs][3]);                    \
            lacc[qs] += (p0 + p1) + (p2 + p3);                                  \
            half4_t pv;                                                         \
            pv[0] = (_Float16)p0; pv[1] = (_Float16)p1;                         \
            pv[2] = (_Float16)p2; pv[3] = (_Float16)p3;                         \
            pb[ks][qs] = pv;                                                    \
        }                                                                       \
        _Pragma("unroll") for (int qs = 0; qs < 4; ++qs)                        \
        _Pragma("unroll") for (int d = 0; d < 4; ++d)                           \
        _Pragma("unroll") for (int ks = 0; ks < 2; ++ks)                        \
            ofr[qs][d] = __builtin_amdgcn_mfma_f32_16x16x16f16(AV[d][ks], pb[ks][qs], ofr[qs][d], 0, 0, 0); \
    }

__global__ __launch_bounds__(512, 2) void attn_w8(
    const float* __restrict__ Q,
    const _Float16* __restrict__ K16,
    const _Float16* __restrict__ VT16,
    float* __restrict__ O)
{
    __shared__ float Ored[512 * 17];                     // 34816 B (epilogue only)
    __shared__ float Lred[512];                          // 2 KB

    const int t    = threadIdx.x;
    const int wave = t >> 6;                   // 0..7
    const int lane = t & 63;
    const int quad = lane >> 4;
    const int l15  = lane & 15;

    const int b   = blockIdx.x & 7;            // batch <-> XCD affinity
    const int qbi = blockIdx.x >> 3;           // query block 0..31
    const int qb  = qbi * 64;
    const int key0 = wave * 256;               // wave's 256-key range

    const _Float16* Kb = K16 + (size_t)b * L_ * D_;
    const _Float16* Vb = VT16 + (size_t)b * D_ * L_;

    // ---- Q B-frags from fp32, pre-scaled by 0.125*log2(e) ----
    half8_t bq[4][2];
    #pragma unroll
    for (int qs = 0; qs < 4; ++qs) {
        const float* qp = Q + ((size_t)b * L_ + qb + qs * 16 + l15) * D_ + quad * 8;
        #pragma unroll
        for (int c = 0; c < 2; ++c) {
            const float4 f0 = *(const float4*)(qp + c * 32);
            const float4 f1 = *(const float4*)(qp + c * 32 + 4);
            bq[qs][c][0] = (_Float16)(f0.x * SCALE_LOG2E);
            bq[qs][c][1] = (_Float16)(f0.y * SCALE_LOG2E);
            bq[qs][c][2] = (_Float16)(f0.z * SCALE_LOG2E);
            bq[qs][c][3] = (_Float16)(f0.w * SCALE_LOG2E);
            bq[qs][c][4] = (_Float16)(f1.x * SCALE_LOG2E);
            bq[qs][c][5] = (_Float16)(f1.y * SCALE_LOG2E);
            bq[qs][c][6] = (_Float16)(f1.z * SCALE_LOG2E);
            bq[qs][c][7] = (_Float16)(f1.w * SCALE_LOG2E);
        }
    }

    f32x4 ofr[4][4];
    #pragma unroll
    for (int qs = 0; qs < 4; ++qs)
        #pragma unroll
        for (int d = 0; d < 4; ++d)
            ofr[qs][d] = (f32x4){0.f, 0.f, 0.f, 0.f};
    float lacc[4] = {0.f, 0.f, 0.f, 0.f};

    // ---- hot loop: 8 tiles of 32 keys, K AND V frags double-buffered ----
    half8_t bkA[2][2], bkB[2][2];
    half4_t avA[4][2], avB[4][2];
    LOADK(key0, bkA);
    LOADV(key0, avA);
    for (int it = 0; it < 4; ++it) {
        const int kb = key0 + it * 64;
        LOADK(kb + 32, bkB);
        LOADV(kb + 32, avB);
        PROC(bkA, avA);
        // final prefetch overruns the wave's range by 32 keys; stays inside
        // the ws mapping (K16 is followed by VT16; ws is far larger) and is
        // never consumed.
        LOADK(kb + 64, bkA);
        LOADV(kb + 64, avA);
        PROC(bkB, avB);
    }

    // ---- l: reduce over quads (each lane holds 4 keys of query qs*16+l15) --
    #pragma unroll
    for (int qs = 0; qs < 4; ++qs) {
        float v = lacc[qs];
        v += __shfl_xor(v, 16, 64);
        v += __shfl_xor(v, 32, 64);
        lacc[qs] = v;
    }
    if (quad == 0) {
        #pragma unroll
        for (int qs = 0; qs < 4; ++qs)
            Lred[wave * 64 + qs * 16 + l15] = lacc[qs];
    }

    // ---- cross-wave combine: 4 passes (one qs each) over shared buffer ----
    #pragma unroll
    for (int qs = 0; qs < 4; ++qs) {
        __syncthreads();   // previous pass's reads (and Lred write) done
        #pragma unroll
        for (int d = 0; d < 4; ++d)
            #pragma unroll
            for (int r = 0; r < 4; ++r)
                Ored[(wave * 64 + lane) * 17 + d * 4 + r] = ofr[qs][d][r];
        __syncthreads();
        if (wave < 4) {
            const float lt = Lred[qs * 16 + l15] + Lred[64 + qs * 16 + l15]
                           + Lred[128 + qs * 16 + l15] + Lred[192 + qs * 16 + l15]
                           + Lred[256 + qs * 16 + l15] + Lred[320 + qs * 16 + l15]
                           + Lred[384 + qs * 16 + l15] + Lred[448 + qs * 16 + l15];
            const float inv = 1.0f / lt;
            f32x4 osum = (f32x4){0.f, 0.f, 0.f, 0.f};
            #pragma unroll
            for (int w2 = 0; w2 < 8; ++w2) {
                const float* src = &Ored[(w2 * 64 + lane) * 17 + wave * 4];
                osum[0] += src[0]; osum[1] += src[1];
                osum[2] += src[2]; osum[3] += src[3];
            }
            float4 outv;
            outv.x = osum[0] * inv; outv.y = osum[1] * inv;
            outv.z = osum[2] * inv; outv.w = osum[3] * inv;
            // query = qb + qs*16 + l15 ; dims = wave*16 + quad*4 .. +4
            *(float4*)&O[((size_t)b * L_ + qb + qs * 16 + l15) * D_ + wave * 16 + quad * 4] = outv;
        }
    }
}

// ------------------------------------------------- fallback (R3, no ws) --
#define KS 72
__global__ __launch_bounds__(NT) void attn_mfma_f16(
    const float* __restrict__ Q, const float* __restrict__ K,
    const float* __restrict__ V, float* __restrict__ O)
{
    __shared__ __align__(16) _Float16 Kt[64 * KS];
    __shared__ __align__(16) _Float16 Vt[D_ * KS];
    __shared__ __align__(16) _Float16 Pt[4][16 * KS];

    const int t = threadIdx.x;
    const int wave = t >> 6, lane = t & 63, quad = lane >> 4, l15 = lane & 15;
    const int bpb = L_ / 64;
    const int b = blockIdx.x / bpb;
    const int qb = (blockIdx.x % bpb) * 64 + wave * 16;
    const size_t boff = (size_t)b * L_ * D_;

    half8_t aq[2];
    {
        const float* qp = Q + boff + (size_t)(qb + l15) * D_ + quad * 8;
        #pragma unroll
        for (int c = 0; c < 2; ++c) {
            const float4* p4 = (const float4*)(qp + c * 32);
            const float4 f0 = p4[0], f1 = p4[1];
            aq[c][0] = (_Float16)f0.x; aq[c][1] = (_Float16)f0.y;
            aq[c][2] = (_Float16)f0.z; aq[c][3] = (_Float16)f0.w;
            aq[c][4] = (_Float16)f1.x; aq[c][5] = (_Float16)f1.y;
            aq[c][6] = (_Float16)f1.z; aq[c][7] = (_Float16)f1.w;
        }
    }
    f32x4 ofr[4];
    #pragma unroll
    for (int d = 0; d < 4; ++d) ofr[d] = (f32x4){0.f, 0.f, 0.f, 0.f};
    float lacc[4] = {0.f, 0.f, 0.f, 0.f};
    const int skey = t & 63, sdg = t >> 6;
    _Float16* Pw = &Pt[wave][0];

    for (int kt = 0; kt < L_ / 64; ++kt) {
        __syncthreads();
        {
            const float4* kg4 = (const float4*)(K + boff + (size_t)(kt * 64 + skey) * D_ + sdg * 16);
            const float4 f0 = kg4[0], f1 = kg4[1], f2 = kg4[2], f3 = kg4[3];
            half8_t w0, w1;
            w0[0] = (_Float16)f0.x; w0[1] = (_Float16)f0.y;
            w0[2] = (_Float16)f0.z; w0[3] = (_Float16)f0.w;
            w0[4] = (_Float16)f1.x; w0[5] = (_Float16)f1.y;
            w0[6] = (_Float16)f1.z; w0[7] = (_Float16)f1.w;
            w1[0] = (_Float16)f2.x; w1[1] = (_Float16)f2.y;
            w1[2] = (_Float16)f2.z; w1[3] = (_Float16)f2.w;
            w1[4] = (_Float16)f3.x; w1[5] = (_Float16)f3.y;
            w1[6] = (_Float16)f3.z; w1[7] = (_Float16)f3.w;
            *(half8_t*)&Kt[skey * KS + sdg * 16] = w0;
            *(half8_t*)&Kt[skey * KS + sdg * 16 + 8] = w1;
        }
        {
            const float4* vg4 = (const float4*)(V + boff + (size_t)(kt * 64 + skey) * D_ + sdg * 16);
            #pragma unroll
            for (int i = 0; i < 4; ++i) {
                const float4 f = vg4[i];
                const int d0 = sdg * 16 + i * 4;
                Vt[(d0 + 0) * KS + skey] = (_Float16)f.x;
                Vt[(d0 + 1) * KS + skey] = (_Float16)f.y;
                Vt[(d0 + 2) * KS + skey] = (_Float16)f.z;
                Vt[(d0 + 3) * KS + skey] = (_Float16)f.w;
            }
        }
        __syncthreads();
        #pragma unroll
        for (int s = 0; s < 4; ++s) {
            const half8_t bk0 = *(const half8_t*)&Kt[(s * 16 + l15) * KS + quad * 8];
            const half8_t bk1 = *(const half8_t*)&Kt[(s * 16 + l15) * KS + 32 + quad * 8];
            f32x4 sc = (f32x4){0.f, 0.f, 0.f, 0.f};
            sc = __builtin_amdgcn_mfma_f32_16x16x32_f16(aq[0], bk0, sc, 0, 0, 0);
            sc = __builtin_amdgcn_mfma_f32_16x16x32_f16(aq[1], bk1, sc, 0, 0, 0);
            #pragma unroll
            for (int r = 0; r < 4; ++r) {
                const float p = __expf(sc[r] * 0.125f);
                lacc[r] += p;
                Pw[(quad * 4 + r) * KS + s * 16 + l15] = (_Float16)p;
            }
        }
        __syncthreads();
        #pragma unroll
        for (int c = 0; c < 2; ++c) {
            const half8_t ap = *(const half8_t*)&Pw[l15 * KS + c * 32 + quad * 8];
            #pragma unroll
            for (int d = 0; d < 4; ++d) {
                const half8_t bv = *(const half8_t*)&Vt[(d * 16 + l15) * KS + c * 32 + quad * 8];
                ofr[d] = __builtin_amdgcn_mfma_f32_16x16x32_f16(ap, bv, ofr[d], 0, 0, 0);
            }
        }
    }
    #pragma unroll
    for (int r = 0; r < 4; ++r) {
        float v = lacc[r];
        v += __shfl_xor(v, 1, 64);
        v += __shfl_xor(v, 2, 64);
        v += __shfl_xor(v, 4, 64);
        v += __shfl_xor(v, 8, 64);
        lacc[r] = v;
    }
    #pragma unroll
    for (int r = 0; r < 4; ++r) {
        const float inv = 1.0f / lacc[r];
        float* orow = O + boff + (size_t)(qb + quad * 4 + r) * D_ + l15;
        #pragma unroll
        for (int d = 0; d < 4; ++d) orow[d * 16] = ofr[d][r] * inv;
    }
}

extern "C" void kernel_launch(void* const* d_in, const int* in_sizes, int n_in,
                              void* d_out, int out_size, void* d_ws, size_t ws_size,
                              hipStream_t stream) {
    const float* Q = (const float*)d_in[0];
    const float* K = (const float*)d_in[1];
    const float* V = (const float*)d_in[2];
    float* O = (float*)d_out;

    if (ws_size >= (size_t)8 * 1024 * 1024) {
        _Float16* K16  = (_Float16*)d_ws;                              // 2 MB
        _Float16* VT16 = K16 + (size_t)B_ * L_ * D_;                   // 2 MB
        prepass<<<768, NT, 0, stream>>>(K, V, K16, VT16);
        attn_w8<<<256, 512, 0, stream>>>(Q, K16, VT16, O);
    } else {
        attn_mfma_f16<<<256, NT, 0, stream>>>(Q, K, V, O);
    }
}